// Round 14
// baseline (574.374 us; speedup 1.0000x reference)
//
#include <hip/hip_runtime.h>
#include <hip/hip_bf16.h>
#include <math.h>

// ---------------------------------------------------------------------------
// B=4, L_IN=1024, D=512, H=8, DK=64, DFF=2048, NL=4, WINDOW=[4,4,4], INNER=5.
// all_size=[1024,256,64,16], L_tot=1360, rows M=5440 padded to M_PAD=5504.
// ---------------------------------------------------------------------------

typedef __attribute__((ext_vector_type(8))) short short8;
typedef __attribute__((ext_vector_type(4))) float f32x4;

__device__ inline ushort f2bf(float x) {
  union { __hip_bfloat16 h; ushort u; } cv; cv.h = __float2bfloat16(x); return cv.u;
}
__device__ inline float bf2f(ushort u) {
  union { unsigned int i; float f; } cv; cv.i = (unsigned)u << 16; return cv.f;
}
__device__ inline float lo16(unsigned u) { union { unsigned i; float f; } c; c.i = u << 16; return c.f; }
__device__ inline float hi16(unsigned u) { union { unsigned i; float f; } c; c.i = u & 0xffff0000u; return c.f; }
__device__ inline unsigned pack2(float a, float b) {
  return (unsigned)f2bf(a) | ((unsigned)f2bf(b) << 16);
}

// tanh-form GELU (max |err| vs exact erf-GELU ~3e-3; well within budget)
__device__ inline float gelu_f(float x) {
  float y = 0.7978845608028654f * (x + 0.044715f * x * x * x);
  float t = __expf(-2.0f * y);
  float th = (1.0f - t) / (1.0f + t);
  return 0.5f * x * (1.0f + th);
}

// bijective XCD-chunk swizzle (m204): round-robin id -> contiguous chunk/XCD
__device__ inline int xcd_chunk(int orig, int nwg) {
  int q = nwg >> 3, r = nwg & 7;
  int xcd = orig & 7, idx = orig >> 3;
  int base = (xcd < r) ? xcd * (q + 1) : r * (q + 1) + (xcd - r) * q;
  return base + idx;
}

#define GLD16(gp, lp)                                                        \
  __builtin_amdgcn_global_load_lds(                                          \
      (const __attribute__((address_space(1))) void*)(gp),                   \
      (__attribute__((address_space(3))) void*)(lp), 16, 0, 0)

// ---------------- embed: circular conv3 + posenc + mark projection ---------
__global__ __launch_bounds__(512) void embed_kernel(
    const float* __restrict__ x_enc, const float* __restrict__ x_mark,
    const float* __restrict__ conv_w, const float* __restrict__ conv_b,
    const float* __restrict__ temp_w, const float* __restrict__ temp_b,
    ushort* __restrict__ e_bf) {
  int bl = blockIdx.x;
  int b = bl >> 10, l = bl & 1023;
  int d = threadIdx.x;
  int lm1 = (l + 1023) & 1023;
  int lp1 = (l + 1) & 1023;
  const float* w  = conv_w + d * 21;
  const float* x0 = x_enc + (size_t)(b * 1024 + lm1) * 7;
  const float* x1 = x_enc + (size_t)(b * 1024 + l)   * 7;
  const float* x2 = x_enc + (size_t)(b * 1024 + lp1) * 7;
  float acc = conv_b[d];
#pragma unroll
  for (int ci = 0; ci < 7; ci++) {
    acc = fmaf(x0[ci], w[ci * 3 + 0], acc);
    acc = fmaf(x1[ci], w[ci * 3 + 1], acc);
    acc = fmaf(x2[ci], w[ci * 3 + 2], acc);
  }
  int j = d >> 1;
  float dv = __expf((float)(2 * j) * (-9.210340371976184f / 512.0f));
  float ang = (float)l * dv;
  float pe = (d & 1) ? __cosf(ang) : __sinf(ang);
  const float* xm = x_mark + (size_t)(b * 1024 + l) * 4;
  float mk = temp_b[d];
  mk = fmaf(xm[0], temp_w[d],        mk);
  mk = fmaf(xm[1], temp_w[512 + d],  mk);
  mk = fmaf(xm[2], temp_w[1024 + d], mk);
  mk = fmaf(xm[3], temp_w[1536 + d], mk);
  e_bf[(size_t)bl * 512 + d] = f2bf(acc + pe + mk);
}

// ---------------- generic weight cast+transpose: f32 [K][N] -> bf16 [N][K] -
__global__ __launch_bounds__(256) void transpose_cast(
    const float* __restrict__ src, ushort* __restrict__ dst,
    int K, int N, size_t src_lstride, size_t dst_lstride) {
  src += (size_t)blockIdx.z * src_lstride;
  dst += (size_t)blockIdx.z * dst_lstride;
  __shared__ float t[32][33];
  int k0 = blockIdx.y * 32, n0 = blockIdx.x * 32;
  int tx = threadIdx.x, ty = threadIdx.y;  // (32,8)
#pragma unroll
  for (int i = 0; i < 4; i++)
    t[ty + i * 8][tx] = src[(size_t)(k0 + ty + i * 8) * N + n0 + tx];
  __syncthreads();
#pragma unroll
  for (int i = 0; i < 4; i++)
    dst[(size_t)(n0 + ty + i * 8) * K + k0 + tx] = f2bf(t[tx][ty + i * 8]);
}

// ---------------- fused 512x512 transposes: wq/wk/wv/fc x 4 layers ----------
__global__ __launch_bounds__(256) void transpose_cast_sq(
    const float* __restrict__ wq, const float* __restrict__ wk,
    const float* __restrict__ wv, const float* __restrict__ fw,
    ushort* __restrict__ qkvw, ushort* __restrict__ fcw) {
  int z = blockIdx.z;                 // kind*4 + layer
  int kind = z >> 2, layer = z & 3;
  const float* src = ((kind == 0) ? wq : (kind == 1) ? wk : (kind == 2) ? wv : fw)
                     + (size_t)layer * 262144;
  ushort* dst = (kind < 3) ? qkvw + (size_t)layer * 786432 + (size_t)kind * 262144
                           : fcw + (size_t)layer * 262144;
  __shared__ float t[32][33];
  int k0 = blockIdx.y * 32, n0 = blockIdx.x * 32;
  int tx = threadIdx.x, ty = threadIdx.y;  // (32,8)
#pragma unroll
  for (int i = 0; i < 4; i++)
    t[ty + i * 8][tx] = src[(size_t)(k0 + ty + i * 8) * 512 + n0 + tx];
  __syncthreads();
#pragma unroll
  for (int i = 0; i < 4; i++)
    dst[(size_t)(n0 + ty + i * 8) * 512 + k0 + tx] = f2bf(t[tx][ty + i * 8]);
}

// ---------------- bf16 MFMA GEMM, 64x64 tile, 8 waves (512 thr), BK=64 -----
// 32KB LDS, 4 blocks/CU x 8 waves = 32 waves/CU (occupancy cap). Wave w owns
// a 16x32 sub-tile: wr=(w&3)*16, wc=(w>>2)*32. 1 GLD16/operand/thread.
// Chunk XOR-swizzle by row&7; XCD-chunk 1D grid (N/64)*(M/64).
__global__ __launch_bounds__(512, 8) void gemm_bf16_t64w8(
    const ushort* __restrict__ A, const ushort* __restrict__ Bt,
    const float* __restrict__ bias, ushort* __restrict__ C,
    int N, int K, int act) {
  __shared__ short As[2][4096];   // 64 rows x 64 k
  __shared__ short Bs[2][4096];
  int nbx = N >> 6;
  int wgid = xcd_chunk(blockIdx.x, gridDim.x);
  int bx = wgid % nbx, by = wgid / nbx;
  int tid = threadIdx.x;
  int w = tid >> 6, lane = tid & 63;
  int bm = by << 6, bn = bx << 6;
  int gch = (tid & 7) ^ ((tid >> 3) & 7);
  const short* Ab = (const short*)A + (size_t)(bm + (tid >> 3)) * K + gch * 8;
  const short* Bb = (const short*)Bt + (size_t)(bn + (tid >> 3)) * K + gch * 8;
  int ldst = (tid & 448) * 8;          // wave-uniform base: w*512 shorts
  int wr = (w & 3) << 4, wc = (w >> 2) << 5;
  int lr = lane & 15, kg = lane >> 4;
  int cs0 = ((kg)     ^ (lane & 7)) * 8;
  int cs1 = ((4 + kg) ^ (lane & 7)) * 8;
  f32x4 acc[2] = {};
#define STG(buf, kt) do {                                                    \
    GLD16(Ab + (kt), &As[buf][ldst]);                                        \
    GLD16(Bb + (kt), &Bs[buf][ldst]); } while (0)
  STG(0, 0);
  __syncthreads();
  int nt = K >> 6;
  for (int t = 0; t < nt; t++) {
    int cur = t & 1;
    if (t + 1 < nt) STG(cur ^ 1, (t + 1) << 6);
    short8 a_[2], b_[2][2];
    {
      int rb = (wr + lr) * 64;
      a_[0] = *(const short8*)&As[cur][rb + cs0];
      a_[1] = *(const short8*)&As[cur][rb + cs1];
    }
#pragma unroll
    for (int n = 0; n < 2; n++) {
      int rb = (wc + n * 16 + lr) * 64;
      b_[n][0] = *(const short8*)&Bs[cur][rb + cs0];
      b_[n][1] = *(const short8*)&Bs[cur][rb + cs1];
    }
#pragma unroll
    for (int ks = 0; ks < 2; ks++)
#pragma unroll
      for (int n = 0; n < 2; n++)
        acc[n] = __builtin_amdgcn_mfma_f32_16x16x32_bf16(a_[ks], b_[n][ks], acc[n], 0, 0, 0);
    __syncthreads();
  }
#undef STG
  int r0 = bm + wr + kg * 4;
  int c0 = bn + wc + lr;
#pragma unroll
  for (int n = 0; n < 2; n++) {
    int col = c0 + n * 16;
    float bv = bias ? bias[col] : 0.0f;
#pragma unroll
    for (int j = 0; j < 4; j++) {
      int row = r0 + j;
      float v = acc[n][j] + bv;
      if (act == 1) v = gelu_f(v);
      C[(size_t)row * N + col] = f2bf(v);
    }
  }
}

// ---------------- bf16 MFMA GEMM, 32x64 tile, BK=64 (small-N, hi-occ) ------
__global__ __launch_bounds__(256) void gemm_bf16_t32(
    const ushort* __restrict__ A, const ushort* __restrict__ Bt,
    const float* __restrict__ bias, ushort* __restrict__ C,
    int N, int K) {
  __shared__ short As[2][2048];   // 32 rows x 64 k
  __shared__ short Bs[2][4096];   // 64 rows x 64 k
  int nbx = N >> 6;
  int wgid = xcd_chunk(blockIdx.x, gridDim.x);
  int bx = wgid % nbx, by = wgid / nbx;
  int tid = threadIdx.x;
  int w = tid >> 6, lane = tid & 63;
  int bm = by << 5, bn = bx << 6;
  int gch = (tid & 7) ^ ((tid >> 3) & 7);
  const short* Ab = (const short*)A + (size_t)(bm + (tid >> 3)) * K + gch * 8;
  const short* Bb = (const short*)Bt + (size_t)(bn + (tid >> 3)) * K + gch * 8;
  int ldst = (tid & 192) * 8;          // wave-uniform: w*512 shorts
  int wr = (w >> 1) << 4, wc = (w & 1) << 5;
  int lr = lane & 15, kg = lane >> 4;
  int cs0 = ((kg)     ^ (lane & 7)) * 8;
  int cs1 = ((4 + kg) ^ (lane & 7)) * 8;
  f32x4 acc[2] = {};
#define STG32(buf, kt) do {                                                  \
    GLD16(Ab + (kt),                  &As[buf][ldst]);                       \
    GLD16(Bb + (kt),                  &Bs[buf][ldst]);                       \
    GLD16(Bb + (kt) + (size_t)32 * K, &Bs[buf][2048 + ldst]); } while (0)
  STG32(0, 0);
  __syncthreads();
  int nt = K >> 6;
  for (int t = 0; t < nt; t++) {
    int cur = t & 1;
    if (t + 1 < nt) STG32(cur ^ 1, (t + 1) << 6);
    short8 a_[2], b_[2][2];
    {
      int rb = (wr + lr) * 64;
      a_[0] = *(const short8*)&As[cur][rb + cs0];
      a_[1] = *(const short8*)&As[cur][rb + cs1];
    }
#pragma unroll
    for (int n = 0; n < 2; n++) {
      int rb = (wc + n * 16 + lr) * 64;
      b_[n][0] = *(const short8*)&Bs[cur][rb + cs0];
      b_[n][1] = *(const short8*)&Bs[cur][rb + cs1];
    }
#pragma unroll
    for (int ks = 0; ks < 2; ks++)
#pragma unroll
      for (int n = 0; n < 2; n++)
        acc[n] = __builtin_amdgcn_mfma_f32_16x16x32_bf16(a_[ks], b_[n][ks], acc[n], 0, 0, 0);
    __syncthreads();
  }
#undef STG32
  int r0 = bm + wr + kg * 4;
  int c0 = bn + wc + lr;
#pragma unroll
  for (int n = 0; n < 2; n++) {
    int col = c0 + n * 16;
    float bv = bias ? bias[col] : 0.0f;
#pragma unroll
    for (int j = 0; j < 4; j++) {
      int row = r0 + j;
      C[(size_t)row * N + col] = f2bf(acc[n][j] + bv);
    }
  }
}

// ---------------- pyramid conv level (bf16 in/out, f32 accumulate) ---------
__global__ __launch_bounds__(64) void pyr_conv(
    const ushort* __restrict__ in, int in_base, int in_bstr,
    ushort* __restrict__ out, int out_base, int out_bstr, int out_len,
    const float* __restrict__ w, const float* __restrict__ bias,
    const float* __restrict__ bng, const float* __restrict__ bnb) {
  int blk = blockIdx.x;
  int b = blk / out_len, to = blk - b * out_len;
  int co = threadIdx.x;
  __shared__ float xin[4][64];
  const ushort* src = in + (size_t)(b * in_bstr + in_base + 4 * to) * 64;
#pragma unroll
  for (int r2 = 0; r2 < 4; r2++) xin[r2][co] = bf2f(src[r2 * 64 + co]);
  __syncthreads();
  const float* wr = w + (size_t)co * 256;
  float acc = bias[co];
#pragma unroll 16
  for (int ci = 0; ci < 64; ci++) {
    acc = fmaf(xin[0][ci], wr[ci * 4 + 0], acc);
    acc = fmaf(xin[1][ci], wr[ci * 4 + 1], acc);
    acc = fmaf(xin[2][ci], wr[ci * 4 + 2], acc);
    acc = fmaf(xin[3][ci], wr[ci * 4 + 3], acc);
  }
  float y = fmaf(bng[co], acc, bnb[co]);
  y = y > 0.0f ? y : expm1f(y);
  out[(size_t)(b * out_bstr + out_base + to) * 64 + co] = f2bf(y);
}

// ---------------- LayerNorm concat (bf16 in), wave-per-row ------------------
__global__ __launch_bounds__(256) void ln_concat(
    const ushort* __restrict__ e_bf, const ushort* __restrict__ pyru,
    const float* __restrict__ g, const float* __restrict__ bta,
    ushort* __restrict__ seq_bf) {
  int r = (blockIdx.x << 2) + (threadIdx.x >> 6);
  int lane = threadIdx.x & 63;
  int b = r / 1360, i = r - b * 1360;
  int c = lane << 3;
  const ushort* src = (i < 1024)
      ? (e_bf + (size_t)(b * 1024 + i) * 512)
      : (pyru + (size_t)(b * 336 + (i - 1024)) * 512);
  uint4 sv = *(const uint4*)(src + c);
  float v[8] = { lo16(sv.x), hi16(sv.x), lo16(sv.y), hi16(sv.y),
                 lo16(sv.z), hi16(sv.z), lo16(sv.w), hi16(sv.w) };
  float sum = v[0]+v[1]+v[2]+v[3]+v[4]+v[5]+v[6]+v[7];
#pragma unroll
  for (int off = 1; off < 64; off <<= 1) sum += __shfl_xor(sum, off);
  float mu = sum * (1.0f / 512.0f);
  float sq = 0.0f;
#pragma unroll
  for (int k = 0; k < 8; k++) { v[k] -= mu; sq += v[k] * v[k]; }
#pragma unroll
  for (int off = 1; off < 64; off <<= 1) sq += __shfl_xor(sq, off);
  float inv = rsqrtf(sq * (1.0f / 512.0f) + 1e-5f);
  float4 g0 = *(const float4*)&g[c],   g1 = *(const float4*)&g[c + 4];
  float4 b0 = *(const float4*)&bta[c], b1 = *(const float4*)&bta[c + 4];
  uint4 pk;
  pk.x = pack2(v[0]*inv*g0.x + b0.x, v[1]*inv*g0.y + b0.y);
  pk.y = pack2(v[2]*inv*g0.z + b0.z, v[3]*inv*g0.w + b0.w);
  pk.z = pack2(v[4]*inv*g1.x + b1.x, v[5]*inv*g1.y + b1.y);
  pk.w = pack2(v[6]*inv*g1.z + b1.z, v[7]*inv*g1.w + b1.w);
  *(uint4*)(seq_bf + (size_t)r * 512 + c) = pk;
}

// ---------------- residual add + LayerNorm on bf16 stream ------------------
__global__ __launch_bounds__(256) void ln_add(
    ushort* __restrict__ seq_bf, const ushort* __restrict__ t1,
    const float* __restrict__ g, const float* __restrict__ bta) {
  int r = (blockIdx.x << 2) + (threadIdx.x >> 6);
  int lane = threadIdx.x & 63;
  int c = lane << 3;
  ushort* row = seq_bf + (size_t)r * 512 + c;
  uint4 sv = *(const uint4*)row;
  uint4 tv = *(const uint4*)(t1 + (size_t)r * 512 + c);
  float v[8] = {
    lo16(sv.x) + lo16(tv.x), hi16(sv.x) + hi16(tv.x),
    lo16(sv.y) + lo16(tv.y), hi16(sv.y) + hi16(tv.y),
    lo16(sv.z) + lo16(tv.z), hi16(sv.z) + hi16(tv.z),
    lo16(sv.w) + lo16(tv.w), hi16(sv.w) + hi16(tv.w) };
  float sum = v[0]+v[1]+v[2]+v[3]+v[4]+v[5]+v[6]+v[7];
#pragma unroll
  for (int off = 1; off < 64; off <<= 1) sum += __shfl_xor(sum, off);
  float mu = sum * (1.0f / 512.0f);
  float sq = 0.0f;
#pragma unroll
  for (int k = 0; k < 8; k++) { v[k] -= mu; sq += v[k] * v[k]; }
#pragma unroll
  for (int off = 1; off < 64; off <<= 1) sq += __shfl_xor(sq, off);
  float inv = rsqrtf(sq * (1.0f / 512.0f) + 1e-5f);
  float4 g0 = *(const float4*)&g[c],   g1 = *(const float4*)&g[c + 4];
  float4 b0 = *(const float4*)&bta[c], b1 = *(const float4*)&bta[c + 4];
  uint4 pk;
  pk.x = pack2(v[0]*inv*g0.x + b0.x, v[1]*inv*g0.y + b0.y);
  pk.y = pack2(v[2]*inv*g0.z + b0.z, v[3]*inv*g0.w + b0.w);
  pk.z = pack2(v[4]*inv*g1.x + b1.x, v[5]*inv*g1.y + b1.y);
  pk.w = pack2(v[6]*inv*g1.z + b1.z, v[7]*inv*g1.w + b1.w);
  *(uint4*)row = pk;
}

// ---------------- final residual+LN fused with output scatter --------------
// Row at pyramid level li serves 4^li output rows (refer-point inverse).
__global__ __launch_bounds__(256) void ln_add_out(
    const ushort* __restrict__ seq_bf, const ushort* __restrict__ t1,
    const float* __restrict__ g, const float* __restrict__ bta,
    float* __restrict__ out) {
  int r = (blockIdx.x << 2) + (threadIdx.x >> 6);
  int lane = threadIdx.x & 63;
  int b = r / 1360, i = r - b * 1360;
  int c = lane << 3;
  uint4 sv = *(const uint4*)(seq_bf + (size_t)r * 512 + c);
  uint4 tv = *(const uint4*)(t1 + (size_t)r * 512 + c);
  float v[8] = {
    lo16(sv.x) + lo16(tv.x), hi16(sv.x) + hi16(tv.x),
    lo16(sv.y) + lo16(tv.y), hi16(sv.y) + hi16(tv.y),
    lo16(sv.z) + lo16(tv.z), hi16(sv.z) + hi16(tv.z),
    lo16(sv.w) + lo16(tv.w), hi16(sv.w) + hi16(tv.w) };
  float sum = v[0]+v[1]+v[2]+v[3]+v[4]+v[5]+v[6]+v[7];
#pragma unroll
  for (int off = 1; off < 64; off <<= 1) sum += __shfl_xor(sum, off);
  float mu = sum * (1.0f / 512.0f);
  float sq = 0.0f;
#pragma unroll
  for (int k = 0; k < 8; k++) { v[k] -= mu; sq += v[k] * v[k]; }
#pragma unroll
  for (int off = 1; off < 64; off <<= 1) sq += __shfl_xor(sq, off);
  float inv = rsqrtf(sq * (1.0f / 512.0f) + 1e-5f);
  float4 g0 = *(const float4*)&g[c],   g1 = *(const float4*)&g[c + 4];
  float4 b0 = *(const float4*)&bta[c], b1 = *(const float4*)&bta[c + 4];
  float4 o0 = make_float4(v[0]*inv*g0.x + b0.x, v[1]*inv*g0.y + b0.y,
                          v[2]*inv*g0.z + b0.z, v[3]*inv*g0.w + b0.w);
  float4 o1 = make_float4(v[4]*inv*g1.x + b1.x, v[5]*inv*g1.y + b1.y,
                          v[6]*inv*g1.z + b1.z, v[7]*inv*g1.w + b1.w);
  int p, q, rep;
  if (i < 1024)      { p = i;        q = 0; rep = 1; }
  else if (i < 1280) { p = i - 1024; q = 1; rep = 4; }
  else if (i < 1344) { p = i - 1280; q = 2; rep = 16; }
  else               { p = i - 1344; q = 3; rep = 64; }
  int i0 = p * rep;
  for (int t = 0; t < rep; t++) {
    float* dst = out + ((size_t)(b * 1024 + i0 + t) * 2048 + q * 512 + c);
    *(float4*)&dst[0] = o0;
    *(float4*)&dst[4] = o1;
  }
}

// ---------------- sparse pyramidal attention (wave-per-head, no LDS) -------
__global__ __launch_bounds__(512) void attn_sparse(
    const ushort* __restrict__ qkv, ushort* __restrict__ o) {
  int r = blockIdx.x;
  int b = r / 1360, i = r - b * 1360;
  int h = threadIdx.x >> 6, lane = threadIdx.x & 63;
  int S, sz, li;
  if (i < 1024)      { li = 0; S = 0;    sz = 1024; }
  else if (i < 1280) { li = 1; S = 1024; sz = 256; }
  else if (i < 1344) { li = 2; S = 1280; sz = 64; }
  else               { li = 3; S = 1344; sz = 16; }
  int p = i - S;
  int lo = p - 2; if (lo < 0) lo = 0;
  int hi = p + 2; if (hi > sz - 1) hi = sz - 1;
  int cnt = hi - lo + 1;
  int nk = cnt + (li > 0 ? 4 : 0) + (li < 3 ? 1 : 0);
  int Sprev = (li == 1) ? 0 : (li == 2) ? 1024 : 1280;
  int Snext = (li == 0) ? 1024 : (li == 1) ? 1280 : 1344;
  int j2 = lane >> 2, c = lane & 3;
  int key;
  if (j2 < cnt)                      key = S + lo + j2;
  else if (li > 0 && j2 - cnt < 4)   key = Sprev + 4 * p + (j2 - cnt);
  else if (li < 3)                   key = Snext + (p >> 2);
  else                               key = S + p;
  float partial = 0.0f;
  {
    const uint4* qv = (const uint4*)(qkv + (size_t)r * 1536 + h * 64 + c * 16);
    const uint4* kv = (const uint4*)(qkv + (size_t)(b * 1360 + key) * 1536 + 512 + h * 64 + c * 16);
#pragma unroll
    for (int cc = 0; cc < 2; cc++) {
      uint4 a = qv[cc], k4 = kv[cc];
      partial = fmaf(lo16(a.x), lo16(k4.x), partial); partial = fmaf(hi16(a.x), hi16(k4.x), partial);
      partial = fmaf(lo16(a.y), lo16(k4.y), partial); partial = fmaf(hi16(a.y), hi16(k4.y), partial);
      partial = fmaf(lo16(a.z), lo16(k4.z), partial); partial = fmaf(hi16(a.z), hi16(k4.z), partial);
      partial = fmaf(lo16(a.w), lo16(k4.w), partial); partial = fmaf(hi16(a.w), hi16(k4.w), partial);
    }
  }
  partial += __shfl_xor(partial, 1);
  partial += __shfl_xor(partial, 2);
  float s = (j2 < nk) ? partial * 0.125f : -1e30f;
  float m = s;
  m = fmaxf(m, __shfl_xor(m, 4));
  m = fmaxf(m, __shfl_xor(m, 8));
  m = fmaxf(m, __shfl_xor(m, 16));
  m = fmaxf(m, __shfl_xor(m, 32));
  float ev = __expf(s - m);
  float den = ev;
  den += __shfl_xor(den, 4);
  den += __shfl_xor(den, 8);
  den += __shfl_xor(den, 16);
  den += __shfl_xor(den, 32);
  float inv = 1.0f / den;                    // den = sum over j2, once each
  float acc = 0.0f;
  for (int j = 0; j < nk; j++) {
    float pj = __shfl(ev, 4 * j) * inv;
    int kj = __shfl(key, 4 * j);
    float vv = bf2f(qkv[(size_t)(b * 1360 + kj) * 1536 + 1024 + h * 64 + lane]);
    acc = fmaf(pj, vv, acc);
  }
  o[(size_t)r * 512 + h * 64 + lane] = f2bf(acc);
}

// ---------------------------------------------------------------------------
extern "C" void kernel_launch(void* const* d_in, const int* in_sizes, int n_in,
                              void* d_out, int out_size, void* d_ws, size_t ws_size,
                              hipStream_t stream) {
  const float* x_enc   = (const float*)d_in[0];
  const float* x_mark  = (const float*)d_in[1];
  const float* conv_w  = (const float*)d_in[2];
  const float* conv_b  = (const float*)d_in[3];
  const float* temp_w  = (const float*)d_in[4];
  const float* temp_b  = (const float*)d_in[5];
  const float* down_w  = (const float*)d_in[6];
  const float* down_b  = (const float*)d_in[7];
  const float* pyr_w   = (const float*)d_in[8];
  const float* pyr_b   = (const float*)d_in[9];
  const float* bn_g    = (const float*)d_in[10];
  const float* bn_b    = (const float*)d_in[11];
  const float* up_w    = (const float*)d_in[12];
  const float* up_b    = (const float*)d_in[13];
  const float* norm_g  = (const float*)d_in[14];
  const float* norm_b  = (const float*)d_in[15];
  const float* wq      = (const float*)d_in[16];
  const float* wk      = (const float*)d_in[17];
  const float* wv      = (const float*)d_in[18];
  const float* fc_w    = (const float*)d_in[19];
  const float* fc_b    = (const float*)d_in[20];
  const float* ln1_g   = (const float*)d_in[21];
  const float* ln1_b   = (const float*)d_in[22];
  const float* w1      = (const float*)d_in[23];
  const float* b1      = (const float*)d_in[24];
  const float* w2      = (const float*)d_in[25];
  const float* b2      = (const float*)d_in[26];
  const float* ln2_g   = (const float*)d_in[27];
  const float* ln2_b   = (const float*)d_in[28];

  // ---- workspace layout (f32-word offsets) ----
  float* ws = (float*)d_ws;
  // prologue (dead before layer loop; aliased by qkv/th region):
  ushort* e_bf    = (ushort*)ws;               // [4096][512] bf16 (1,048,576 w)
  ushort* tmp0_bf = (ushort*)(ws + 1048576);   // [4096][64] bf16
  ushort* pyrf_bf = (ushort*)(ws + 1179648);   // [1344][64] bf16
  ushort* pyru_bf = (ushort*)(ws + 1222656);   // [1344][512] bf16
  // layer-loop:
  ushort* qkv_bf = (ushort*)ws;                // [5504][1536] bf16
  ushort* o_bf   = (ushort*)(ws + 4227072);    // [5504][512] bf16
  ushort* th_bf  = (ushort*)ws;                // [5504][2048] bf16
  ushort* t1     = (ushort*)(ws + 5636096);    // [5504][512] bf16
  ushort* dwt    = (ushort*)(ws + 7045120);    // down_w^T [64][512]
  ushort* uwt    = (ushort*)(ws + 7061504);    // up_w^T  [512][64]
  ushort* seq_bf = (ushort*)(ws + 11272192);   // [5504][512] bf16
  ushort* qkvw   = (ushort*)(ws + 12681216);   // 4 x [1536][512] bf16
  ushort* fcw    = (ushort*)(ws + 14254080);   // 4 x [512][512] bf16
  ushort* w1t    = (ushort*)(ws + 14778368);   // 4 x [2048][512] bf16
  ushort* w2t    = (ushort*)(ws + 16875520);   // 4 x [512][2048] bf16

  // ---- weight cast+transpose (once per call) ----
  dim3 tb(32, 8);
  transpose_cast_sq<<<dim3(16, 16, 16), tb, 0, stream>>>(wq, wk, wv, fc_w, qkvw, fcw);
  transpose_cast<<<dim3(64, 16, 4), tb, 0, stream>>>(w1, w1t, 512, 2048, 1048576, 1048576);
  transpose_cast<<<dim3(16, 64, 4), tb, 0, stream>>>(w2, w2t, 2048, 512, 1048576, 1048576);
  transpose_cast<<<dim3(2, 16, 1), tb, 0, stream>>>(down_w, dwt, 512, 64, 0, 0);
  transpose_cast<<<dim3(16, 2, 1), tb, 0, stream>>>(up_w, uwt, 64, 512, 0, 0);

  // ---- prologue (all-bf16 MFMA path) ----
  embed_kernel<<<4096, 512, 0, stream>>>(x_enc, x_mark, conv_w, conv_b,
                                         temp_w, temp_b, e_bf);
  gemm_bf16_t32<<<128, 256, 0, stream>>>(e_bf, dwt, down_b, tmp0_bf, 64, 512);
  pyr_conv<<<4 * 256, 64, 0, stream>>>(tmp0_bf, 0, 1024, pyrf_bf, 0, 336, 256,
                                       pyr_w, pyr_b, bn_g, bn_b);
  pyr_conv<<<4 * 64, 64, 0, stream>>>(pyrf_bf, 0, 336, pyrf_bf, 256, 336, 64,
                                      pyr_w + 16384, pyr_b + 64, bn_g + 64, bn_b + 64);
  pyr_conv<<<4 * 16, 64, 0, stream>>>(pyrf_bf, 256, 336, pyrf_bf, 320, 336, 16,
                                      pyr_w + 32768, pyr_b + 128, bn_g + 128, bn_b + 128);
  gemm_bf16_t32<<<8 * 42, 256, 0, stream>>>(pyrf_bf, uwt, up_b, pyru_bf, 512, 64);
  ln_concat<<<1360, 256, 0, stream>>>(e_bf, pyru_bf, norm_g, norm_b, seq_bf);

  // ---- layers ----
  for (int l = 0; l < 4; l++) {
    gemm_bf16_t64w8<<<24 * 86, 512, 0, stream>>>(seq_bf, qkvw + (size_t)l * 786432,
                                                 nullptr, qkv_bf, 1536, 512, 0);
    attn_sparse<<<5440, 512, 0, stream>>>(qkv_bf, o_bf);
    gemm_bf16_t32<<<8 * 172, 256, 0, stream>>>(o_bf, fcw + (size_t)l * 262144,
                                               fc_b + l * 512, t1, 512, 512);
    ln_add<<<1360, 256, 0, stream>>>(seq_bf, t1, ln1_g + l * 512, ln1_b + l * 512);
    gemm_bf16_t64w8<<<32 * 86, 512, 0, stream>>>(seq_bf, w1t + (size_t)l * 1048576,
                                                 b1 + l * 2048, th_bf, 2048, 512, 1);
    gemm_bf16_t32<<<8 * 172, 256, 0, stream>>>(th_bf, w2t + (size_t)l * 1048576,
                                               b2 + l * 512, t1, 512, 2048);
    if (l < 3) {
      ln_add<<<1360, 256, 0, stream>>>(seq_bf, t1, ln2_g + l * 512, ln2_b + l * 512);
    } else {
      ln_add_out<<<1360, 256, 0, stream>>>(seq_bf, t1, ln2_g + l * 512,
                                           ln2_b + l * 512, (float*)d_out);
    }
  }
}

// Round 15
// 510.679 us; speedup vs baseline: 1.1247x; 1.1247x over previous
//
#include <hip/hip_runtime.h>
#include <hip/hip_bf16.h>
#include <math.h>

// ---------------------------------------------------------------------------
// B=4, L_IN=1024, D=512, H=8, DK=64, DFF=2048, NL=4, WINDOW=[4,4,4], INNER=5.
// all_size=[1024,256,64,16], L_tot=1360, rows M=5440 padded to M_PAD=5504.
// ---------------------------------------------------------------------------

typedef __attribute__((ext_vector_type(8))) short short8;
typedef __attribute__((ext_vector_type(4))) float f32x4;

__device__ inline ushort f2bf(float x) {
  union { __hip_bfloat16 h; ushort u; } cv; cv.h = __float2bfloat16(x); return cv.u;
}
__device__ inline float bf2f(ushort u) {
  union { unsigned int i; float f; } cv; cv.i = (unsigned)u << 16; return cv.f;
}
__device__ inline float lo16(unsigned u) { union { unsigned i; float f; } c; c.i = u << 16; return c.f; }
__device__ inline float hi16(unsigned u) { union { unsigned i; float f; } c; c.i = u & 0xffff0000u; return c.f; }
__device__ inline unsigned pack2(float a, float b) {
  return (unsigned)f2bf(a) | ((unsigned)f2bf(b) << 16);
}

// tanh-form GELU (max |err| vs exact erf-GELU ~3e-3; well within budget)
__device__ inline float gelu_f(float x) {
  float y = 0.7978845608028654f * (x + 0.044715f * x * x * x);
  float t = __expf(-2.0f * y);
  float th = (1.0f - t) / (1.0f + t);
  return 0.5f * x * (1.0f + th);
}

// bijective XCD-chunk swizzle (m204): round-robin id -> contiguous chunk/XCD
__device__ inline int xcd_chunk(int orig, int nwg) {
  int q = nwg >> 3, r = nwg & 7;
  int xcd = orig & 7, idx = orig >> 3;
  int base = (xcd < r) ? xcd * (q + 1) : r * (q + 1) + (xcd - r) * q;
  return base + idx;
}

#define GLD16(gp, lp)                                                        \
  __builtin_amdgcn_global_load_lds(                                          \
      (const __attribute__((address_space(1))) void*)(gp),                   \
      (__attribute__((address_space(3))) void*)(lp), 16, 0, 0)

// ---------------- embed: circular conv3 + posenc + mark projection ---------
__global__ __launch_bounds__(512) void embed_kernel(
    const float* __restrict__ x_enc, const float* __restrict__ x_mark,
    const float* __restrict__ conv_w, const float* __restrict__ conv_b,
    const float* __restrict__ temp_w, const float* __restrict__ temp_b,
    ushort* __restrict__ e_bf) {
  int bl = blockIdx.x;
  int b = bl >> 10, l = bl & 1023;
  int d = threadIdx.x;
  int lm1 = (l + 1023) & 1023;
  int lp1 = (l + 1) & 1023;
  const float* w  = conv_w + d * 21;
  const float* x0 = x_enc + (size_t)(b * 1024 + lm1) * 7;
  const float* x1 = x_enc + (size_t)(b * 1024 + l)   * 7;
  const float* x2 = x_enc + (size_t)(b * 1024 + lp1) * 7;
  float acc = conv_b[d];
#pragma unroll
  for (int ci = 0; ci < 7; ci++) {
    acc = fmaf(x0[ci], w[ci * 3 + 0], acc);
    acc = fmaf(x1[ci], w[ci * 3 + 1], acc);
    acc = fmaf(x2[ci], w[ci * 3 + 2], acc);
  }
  int j = d >> 1;
  float dv = __expf((float)(2 * j) * (-9.210340371976184f / 512.0f));
  float ang = (float)l * dv;
  float pe = (d & 1) ? __cosf(ang) : __sinf(ang);
  const float* xm = x_mark + (size_t)(b * 1024 + l) * 4;
  float mk = temp_b[d];
  mk = fmaf(xm[0], temp_w[d],        mk);
  mk = fmaf(xm[1], temp_w[512 + d],  mk);
  mk = fmaf(xm[2], temp_w[1024 + d], mk);
  mk = fmaf(xm[3], temp_w[1536 + d], mk);
  e_bf[(size_t)bl * 512 + d] = f2bf(acc + pe + mk);
}

// ---------------- generic weight cast+transpose: f32 [K][N] -> bf16 [N][K] -
__global__ __launch_bounds__(256) void transpose_cast(
    const float* __restrict__ src, ushort* __restrict__ dst,
    int K, int N, size_t src_lstride, size_t dst_lstride) {
  src += (size_t)blockIdx.z * src_lstride;
  dst += (size_t)blockIdx.z * dst_lstride;
  __shared__ float t[32][33];
  int k0 = blockIdx.y * 32, n0 = blockIdx.x * 32;
  int tx = threadIdx.x, ty = threadIdx.y;  // (32,8)
#pragma unroll
  for (int i = 0; i < 4; i++)
    t[ty + i * 8][tx] = src[(size_t)(k0 + ty + i * 8) * N + n0 + tx];
  __syncthreads();
#pragma unroll
  for (int i = 0; i < 4; i++)
    dst[(size_t)(n0 + ty + i * 8) * K + k0 + tx] = f2bf(t[tx][ty + i * 8]);
}

// ---------------- fused 512x512 transposes: wq/wk/wv/fc x 4 layers ----------
__global__ __launch_bounds__(256) void transpose_cast_sq(
    const float* __restrict__ wq, const float* __restrict__ wk,
    const float* __restrict__ wv, const float* __restrict__ fw,
    ushort* __restrict__ qkvw, ushort* __restrict__ fcw) {
  int z = blockIdx.z;                 // kind*4 + layer
  int kind = z >> 2, layer = z & 3;
  const float* src = ((kind == 0) ? wq : (kind == 1) ? wk : (kind == 2) ? wv : fw)
                     + (size_t)layer * 262144;
  ushort* dst = (kind < 3) ? qkvw + (size_t)layer * 786432 + (size_t)kind * 262144
                           : fcw + (size_t)layer * 262144;
  __shared__ float t[32][33];
  int k0 = blockIdx.y * 32, n0 = blockIdx.x * 32;
  int tx = threadIdx.x, ty = threadIdx.y;  // (32,8)
#pragma unroll
  for (int i = 0; i < 4; i++)
    t[ty + i * 8][tx] = src[(size_t)(k0 + ty + i * 8) * 512 + n0 + tx];
  __syncthreads();
#pragma unroll
  for (int i = 0; i < 4; i++)
    dst[(size_t)(n0 + ty + i * 8) * 512 + k0 + tx] = f2bf(t[tx][ty + i * 8]);
}

// ---------------- bf16 MFMA GEMM, 64x64 tile, 8 waves (512 thr), BK=64 -----
// 32KB LDS, 4 blocks/CU x 8 waves = 32 waves/CU (occupancy cap). Wave w owns
// a 16x32 sub-tile: wr=(w&3)*16, wc=(w>>2)*32. 1 GLD16/operand/thread.
// Chunk XOR-swizzle by row&7; XCD-chunk 1D grid (N/64)*(M/64).
__global__ __launch_bounds__(512, 8) void gemm_bf16_t64w8(
    const ushort* __restrict__ A, const ushort* __restrict__ Bt,
    const float* __restrict__ bias, ushort* __restrict__ C,
    int N, int K, int act) {
  __shared__ short As[2][4096];   // 64 rows x 64 k
  __shared__ short Bs[2][4096];
  int nbx = N >> 6;
  int wgid = xcd_chunk(blockIdx.x, gridDim.x);
  int bx = wgid % nbx, by = wgid / nbx;
  int tid = threadIdx.x;
  int w = tid >> 6, lane = tid & 63;
  int bm = by << 6, bn = bx << 6;
  int gch = (tid & 7) ^ ((tid >> 3) & 7);
  const short* Ab = (const short*)A + (size_t)(bm + (tid >> 3)) * K + gch * 8;
  const short* Bb = (const short*)Bt + (size_t)(bn + (tid >> 3)) * K + gch * 8;
  int ldst = (tid & 448) * 8;          // wave-uniform base: w*512 shorts
  int wr = (w & 3) << 4, wc = (w >> 2) << 5;
  int lr = lane & 15, kg = lane >> 4;
  int cs0 = ((kg)     ^ (lane & 7)) * 8;
  int cs1 = ((4 + kg) ^ (lane & 7)) * 8;
  f32x4 acc[2] = {};
#define STG(buf, kt) do {                                                    \
    GLD16(Ab + (kt), &As[buf][ldst]);                                        \
    GLD16(Bb + (kt), &Bs[buf][ldst]); } while (0)
  STG(0, 0);
  __syncthreads();
  int nt = K >> 6;
  for (int t = 0; t < nt; t++) {
    int cur = t & 1;
    if (t + 1 < nt) STG(cur ^ 1, (t + 1) << 6);
    short8 a_[2], b_[2][2];
    {
      int rb = (wr + lr) * 64;
      a_[0] = *(const short8*)&As[cur][rb + cs0];
      a_[1] = *(const short8*)&As[cur][rb + cs1];
    }
#pragma unroll
    for (int n = 0; n < 2; n++) {
      int rb = (wc + n * 16 + lr) * 64;
      b_[n][0] = *(const short8*)&Bs[cur][rb + cs0];
      b_[n][1] = *(const short8*)&Bs[cur][rb + cs1];
    }
#pragma unroll
    for (int ks = 0; ks < 2; ks++)
#pragma unroll
      for (int n = 0; n < 2; n++)
        acc[n] = __builtin_amdgcn_mfma_f32_16x16x32_bf16(a_[ks], b_[n][ks], acc[n], 0, 0, 0);
    __syncthreads();
  }
#undef STG
  int r0 = bm + wr + kg * 4;
  int c0 = bn + wc + lr;
#pragma unroll
  for (int n = 0; n < 2; n++) {
    int col = c0 + n * 16;
    float bv = bias ? bias[col] : 0.0f;
#pragma unroll
    for (int j = 0; j < 4; j++) {
      int row = r0 + j;
      float v = acc[n][j] + bv;
      if (act == 1) v = gelu_f(v);
      C[(size_t)row * N + col] = f2bf(v);
    }
  }
}

// ---------------- bf16 MFMA GEMM, 32x64 tile, BK=64 (small-N, hi-occ) ------
__global__ __launch_bounds__(256) void gemm_bf16_t32(
    const ushort* __restrict__ A, const ushort* __restrict__ Bt,
    const float* __restrict__ bias, ushort* __restrict__ C,
    int N, int K) {
  __shared__ short As[2][2048];   // 32 rows x 64 k
  __shared__ short Bs[2][4096];   // 64 rows x 64 k
  int nbx = N >> 6;
  int wgid = xcd_chunk(blockIdx.x, gridDim.x);
  int bx = wgid % nbx, by = wgid / nbx;
  int tid = threadIdx.x;
  int w = tid >> 6, lane = tid & 63;
  int bm = by << 5, bn = bx << 6;
  int gch = (tid & 7) ^ ((tid >> 3) & 7);
  const short* Ab = (const short*)A + (size_t)(bm + (tid >> 3)) * K + gch * 8;
  const short* Bb = (const short*)Bt + (size_t)(bn + (tid >> 3)) * K + gch * 8;
  int ldst = (tid & 192) * 8;          // wave-uniform: w*512 shorts
  int wr = (w >> 1) << 4, wc = (w & 1) << 5;
  int lr = lane & 15, kg = lane >> 4;
  int cs0 = ((kg)     ^ (lane & 7)) * 8;
  int cs1 = ((4 + kg) ^ (lane & 7)) * 8;
  f32x4 acc[2] = {};
#define STG32(buf, kt) do {                                                  \
    GLD16(Ab + (kt),                  &As[buf][ldst]);                       \
    GLD16(Bb + (kt),                  &Bs[buf][ldst]);                       \
    GLD16(Bb + (kt) + (size_t)32 * K, &Bs[buf][2048 + ldst]); } while (0)
  STG32(0, 0);
  __syncthreads();
  int nt = K >> 6;
  for (int t = 0; t < nt; t++) {
    int cur = t & 1;
    if (t + 1 < nt) STG32(cur ^ 1, (t + 1) << 6);
    short8 a_[2], b_[2][2];
    {
      int rb = (wr + lr) * 64;
      a_[0] = *(const short8*)&As[cur][rb + cs0];
      a_[1] = *(const short8*)&As[cur][rb + cs1];
    }
#pragma unroll
    for (int n = 0; n < 2; n++) {
      int rb = (wc + n * 16 + lr) * 64;
      b_[n][0] = *(const short8*)&Bs[cur][rb + cs0];
      b_[n][1] = *(const short8*)&Bs[cur][rb + cs1];
    }
#pragma unroll
    for (int ks = 0; ks < 2; ks++)
#pragma unroll
      for (int n = 0; n < 2; n++)
        acc[n] = __builtin_amdgcn_mfma_f32_16x16x32_bf16(a_[ks], b_[n][ks], acc[n], 0, 0, 0);
    __syncthreads();
  }
#undef STG32
  int r0 = bm + wr + kg * 4;
  int c0 = bn + wc + lr;
#pragma unroll
  for (int n = 0; n < 2; n++) {
    int col = c0 + n * 16;
    float bv = bias ? bias[col] : 0.0f;
#pragma unroll
    for (int j = 0; j < 4; j++) {
      int row = r0 + j;
      C[(size_t)row * N + col] = f2bf(acc[n][j] + bv);
    }
  }
}

// ---------------- pyramid conv level (bf16 in/out, f32 accumulate) ---------
__global__ __launch_bounds__(64) void pyr_conv(
    const ushort* __restrict__ in, int in_base, int in_bstr,
    ushort* __restrict__ out, int out_base, int out_bstr, int out_len,
    const float* __restrict__ w, const float* __restrict__ bias,
    const float* __restrict__ bng, const float* __restrict__ bnb) {
  int blk = blockIdx.x;
  int b = blk / out_len, to = blk - b * out_len;
  int co = threadIdx.x;
  __shared__ float xin[4][64];
  const ushort* src = in + (size_t)(b * in_bstr + in_base + 4 * to) * 64;
#pragma unroll
  for (int r2 = 0; r2 < 4; r2++) xin[r2][co] = bf2f(src[r2 * 64 + co]);
  __syncthreads();
  const float* wr = w + (size_t)co * 256;
  float acc = bias[co];
#pragma unroll 16
  for (int ci = 0; ci < 64; ci++) {
    acc = fmaf(xin[0][ci], wr[ci * 4 + 0], acc);
    acc = fmaf(xin[1][ci], wr[ci * 4 + 1], acc);
    acc = fmaf(xin[2][ci], wr[ci * 4 + 2], acc);
    acc = fmaf(xin[3][ci], wr[ci * 4 + 3], acc);
  }
  float y = fmaf(bng[co], acc, bnb[co]);
  y = y > 0.0f ? y : expm1f(y);
  out[(size_t)(b * out_bstr + out_base + to) * 64 + co] = f2bf(y);
}

// ---------------- LayerNorm concat (bf16 in), wave-per-row ------------------
__global__ __launch_bounds__(256) void ln_concat(
    const ushort* __restrict__ e_bf, const ushort* __restrict__ pyru,
    const float* __restrict__ g, const float* __restrict__ bta,
    ushort* __restrict__ seq_bf) {
  int r = (blockIdx.x << 2) + (threadIdx.x >> 6);
  int lane = threadIdx.x & 63;
  int b = r / 1360, i = r - b * 1360;
  int c = lane << 3;
  const ushort* src = (i < 1024)
      ? (e_bf + (size_t)(b * 1024 + i) * 512)
      : (pyru + (size_t)(b * 336 + (i - 1024)) * 512);
  uint4 sv = *(const uint4*)(src + c);
  float v[8] = { lo16(sv.x), hi16(sv.x), lo16(sv.y), hi16(sv.y),
                 lo16(sv.z), hi16(sv.z), lo16(sv.w), hi16(sv.w) };
  float sum = v[0]+v[1]+v[2]+v[3]+v[4]+v[5]+v[6]+v[7];
#pragma unroll
  for (int off = 1; off < 64; off <<= 1) sum += __shfl_xor(sum, off);
  float mu = sum * (1.0f / 512.0f);
  float sq = 0.0f;
#pragma unroll
  for (int k = 0; k < 8; k++) { v[k] -= mu; sq += v[k] * v[k]; }
#pragma unroll
  for (int off = 1; off < 64; off <<= 1) sq += __shfl_xor(sq, off);
  float inv = rsqrtf(sq * (1.0f / 512.0f) + 1e-5f);
  float4 g0 = *(const float4*)&g[c],   g1 = *(const float4*)&g[c + 4];
  float4 b0 = *(const float4*)&bta[c], b1 = *(const float4*)&bta[c + 4];
  uint4 pk;
  pk.x = pack2(v[0]*inv*g0.x + b0.x, v[1]*inv*g0.y + b0.y);
  pk.y = pack2(v[2]*inv*g0.z + b0.z, v[3]*inv*g0.w + b0.w);
  pk.z = pack2(v[4]*inv*g1.x + b1.x, v[5]*inv*g1.y + b1.y);
  pk.w = pack2(v[6]*inv*g1.z + b1.z, v[7]*inv*g1.w + b1.w);
  *(uint4*)(seq_bf + (size_t)r * 512 + c) = pk;
}

// ---------------- residual add + LayerNorm on bf16 stream ------------------
__global__ __launch_bounds__(256) void ln_add(
    ushort* __restrict__ seq_bf, const ushort* __restrict__ t1,
    const float* __restrict__ g, const float* __restrict__ bta) {
  int r = (blockIdx.x << 2) + (threadIdx.x >> 6);
  int lane = threadIdx.x & 63;
  int c = lane << 3;
  ushort* row = seq_bf + (size_t)r * 512 + c;
  uint4 sv = *(const uint4*)row;
  uint4 tv = *(const uint4*)(t1 + (size_t)r * 512 + c);
  float v[8] = {
    lo16(sv.x) + lo16(tv.x), hi16(sv.x) + hi16(tv.x),
    lo16(sv.y) + lo16(tv.y), hi16(sv.y) + hi16(tv.y),
    lo16(sv.z) + lo16(tv.z), hi16(sv.z) + hi16(tv.z),
    lo16(sv.w) + lo16(tv.w), hi16(sv.w) + hi16(tv.w) };
  float sum = v[0]+v[1]+v[2]+v[3]+v[4]+v[5]+v[6]+v[7];
#pragma unroll
  for (int off = 1; off < 64; off <<= 1) sum += __shfl_xor(sum, off);
  float mu = sum * (1.0f / 512.0f);
  float sq = 0.0f;
#pragma unroll
  for (int k = 0; k < 8; k++) { v[k] -= mu; sq += v[k] * v[k]; }
#pragma unroll
  for (int off = 1; off < 64; off <<= 1) sq += __shfl_xor(sq, off);
  float inv = rsqrtf(sq * (1.0f / 512.0f) + 1e-5f);
  float4 g0 = *(const float4*)&g[c],   g1 = *(const float4*)&g[c + 4];
  float4 b0 = *(const float4*)&bta[c], b1 = *(const float4*)&bta[c + 4];
  uint4 pk;
  pk.x = pack2(v[0]*inv*g0.x + b0.x, v[1]*inv*g0.y + b0.y);
  pk.y = pack2(v[2]*inv*g0.z + b0.z, v[3]*inv*g0.w + b0.w);
  pk.z = pack2(v[4]*inv*g1.x + b1.x, v[5]*inv*g1.y + b1.y);
  pk.w = pack2(v[6]*inv*g1.z + b1.z, v[7]*inv*g1.w + b1.w);
  *(uint4*)row = pk;
}

// ---------------- sparse pyramidal attention (wave-per-head, no LDS) -------
__global__ __launch_bounds__(512) void attn_sparse(
    const ushort* __restrict__ qkv, ushort* __restrict__ o) {
  int r = blockIdx.x;
  int b = r / 1360, i = r - b * 1360;
  int h = threadIdx.x >> 6, lane = threadIdx.x & 63;
  int S, sz, li;
  if (i < 1024)      { li = 0; S = 0;    sz = 1024; }
  else if (i < 1280) { li = 1; S = 1024; sz = 256; }
  else if (i < 1344) { li = 2; S = 1280; sz = 64; }
  else               { li = 3; S = 1344; sz = 16; }
  int p = i - S;
  int lo = p - 2; if (lo < 0) lo = 0;
  int hi = p + 2; if (hi > sz - 1) hi = sz - 1;
  int cnt = hi - lo + 1;
  int nk = cnt + (li > 0 ? 4 : 0) + (li < 3 ? 1 : 0);
  int Sprev = (li == 1) ? 0 : (li == 2) ? 1024 : 1280;
  int Snext = (li == 0) ? 1024 : (li == 1) ? 1280 : 1344;
  int j2 = lane >> 2, c = lane & 3;
  int key;
  if (j2 < cnt)                      key = S + lo + j2;
  else if (li > 0 && j2 - cnt < 4)   key = Sprev + 4 * p + (j2 - cnt);
  else if (li < 3)                   key = Snext + (p >> 2);
  else                               key = S + p;
  float partial = 0.0f;
  {
    const uint4* qv = (const uint4*)(qkv + (size_t)r * 1536 + h * 64 + c * 16);
    const uint4* kv = (const uint4*)(qkv + (size_t)(b * 1360 + key) * 1536 + 512 + h * 64 + c * 16);
#pragma unroll
    for (int cc = 0; cc < 2; cc++) {
      uint4 a = qv[cc], k4 = kv[cc];
      partial = fmaf(lo16(a.x), lo16(k4.x), partial); partial = fmaf(hi16(a.x), hi16(k4.x), partial);
      partial = fmaf(lo16(a.y), lo16(k4.y), partial); partial = fmaf(hi16(a.y), hi16(k4.y), partial);
      partial = fmaf(lo16(a.z), lo16(k4.z), partial); partial = fmaf(hi16(a.z), hi16(k4.z), partial);
      partial = fmaf(lo16(a.w), lo16(k4.w), partial); partial = fmaf(hi16(a.w), hi16(k4.w), partial);
    }
  }
  partial += __shfl_xor(partial, 1);
  partial += __shfl_xor(partial, 2);
  float s = (j2 < nk) ? partial * 0.125f : -1e30f;
  float m = s;
  m = fmaxf(m, __shfl_xor(m, 4));
  m = fmaxf(m, __shfl_xor(m, 8));
  m = fmaxf(m, __shfl_xor(m, 16));
  m = fmaxf(m, __shfl_xor(m, 32));
  float ev = __expf(s - m);
  float den = ev;
  den += __shfl_xor(den, 4);
  den += __shfl_xor(den, 8);
  den += __shfl_xor(den, 16);
  den += __shfl_xor(den, 32);
  float inv = 1.0f / den;                    // den = sum over j2, once each
  float acc = 0.0f;
  for (int j = 0; j < nk; j++) {
    float pj = __shfl(ev, 4 * j) * inv;
    int kj = __shfl(key, 4 * j);
    float vv = bf2f(qkv[(size_t)(b * 1360 + kj) * 1536 + 1024 + h * 64 + lane]);
    acc = fmaf(pj, vv, acc);
  }
  o[(size_t)r * 512 + h * 64 + lane] = f2bf(acc);
}

// ---------------- output gather (bf16 stream -> f32 out), vectorized -------
__global__ __launch_bounds__(512) void gather_out(
    const ushort* __restrict__ seq_bf, float* __restrict__ out) {
  int bl = blockIdx.x;
  int b = bl >> 10, i = bl & 1023;
  int t = threadIdx.x;
  int q = t >> 7, e4 = (t & 127) << 2;
  int src_row = (q == 0) ? i
              : (q == 1) ? 1024 + (i >> 2)
              : (q == 2) ? 1280 + (i >> 4)
              :            1344 + (i >> 6);
  size_t base = (size_t)b * 1360;
  const ushort* sp = seq_bf + ((base + src_row) * 512 + e4);
  uint2 sv = *(const uint2*)sp;
  float4 ov;
  ov.x = lo16(sv.x); ov.y = hi16(sv.x);
  ov.z = lo16(sv.y); ov.w = hi16(sv.y);
  *(float4*)&out[(size_t)bl * 2048 + q * 512 + e4] = ov;
}

// ---------------------------------------------------------------------------
extern "C" void kernel_launch(void* const* d_in, const int* in_sizes, int n_in,
                              void* d_out, int out_size, void* d_ws, size_t ws_size,
                              hipStream_t stream) {
  const float* x_enc   = (const float*)d_in[0];
  const float* x_mark  = (const float*)d_in[1];
  const float* conv_w  = (const float*)d_in[2];
  const float* conv_b  = (const float*)d_in[3];
  const float* temp_w  = (const float*)d_in[4];
  const float* temp_b  = (const float*)d_in[5];
  const float* down_w  = (const float*)d_in[6];
  const float* down_b  = (const float*)d_in[7];
  const float* pyr_w   = (const float*)d_in[8];
  const float* pyr_b   = (const float*)d_in[9];
  const float* bn_g    = (const float*)d_in[10];
  const float* bn_b    = (const float*)d_in[11];
  const float* up_w    = (const float*)d_in[12];
  const float* up_b    = (const float*)d_in[13];
  const float* norm_g  = (const float*)d_in[14];
  const float* norm_b  = (const float*)d_in[15];
  const float* wq      = (const float*)d_in[16];
  const float* wk      = (const float*)d_in[17];
  const float* wv      = (const float*)d_in[18];
  const float* fc_w    = (const float*)d_in[19];
  const float* fc_b    = (const float*)d_in[20];
  const float* ln1_g   = (const float*)d_in[21];
  const float* ln1_b   = (const float*)d_in[22];
  const float* w1      = (const float*)d_in[23];
  const float* b1      = (const float*)d_in[24];
  const float* w2      = (const float*)d_in[25];
  const float* b2      = (const float*)d_in[26];
  const float* ln2_g   = (const float*)d_in[27];
  const float* ln2_b   = (const float*)d_in[28];

  // ---- workspace layout (f32-word offsets) ----
  float* ws = (float*)d_ws;
  // prologue (dead before layer loop; aliased by qkv/th region):
  ushort* e_bf    = (ushort*)ws;               // [4096][512] bf16
  ushort* tmp0_bf = (ushort*)(ws + 1048576);   // [4096][64] bf16
  ushort* pyrf_bf = (ushort*)(ws + 1179648);   // [1344][64] bf16
  ushort* pyru_bf = (ushort*)(ws + 1222656);   // [1344][512] bf16
  // layer-loop:
  ushort* qkv_bf = (ushort*)ws;                // [5504][1536] bf16
  ushort* o_bf   = (ushort*)(ws + 4227072);    // [5504][512] bf16
  ushort* th_bf  = (ushort*)ws;                // [5504][2048] bf16
  ushort* t1     = (ushort*)(ws + 5636096);    // [5504][512] bf16
  ushort* dwt    = (ushort*)(ws + 7045120);    // down_w^T [64][512]
  ushort* uwt    = (ushort*)(ws + 7061504);    // up_w^T  [512][64]
  ushort* seq_bf = (ushort*)(ws + 11272192);   // [5504][512] bf16
  ushort* qkvw   = (ushort*)(ws + 12681216);   // 4 x [1536][512] bf16
  ushort* fcw    = (ushort*)(ws + 14254080);   // 4 x [512][512] bf16
  ushort* w1t    = (ushort*)(ws + 14778368);   // 4 x [2048][512] bf16
  ushort* w2t    = (ushort*)(ws + 16875520);   // 4 x [512][2048] bf16

  // ---- weight cast+transpose (once per call) ----
  dim3 tb(32, 8);
  transpose_cast_sq<<<dim3(16, 16, 16), tb, 0, stream>>>(wq, wk, wv, fc_w, qkvw, fcw);
  transpose_cast<<<dim3(64, 16, 4), tb, 0, stream>>>(w1, w1t, 512, 2048, 1048576, 1048576);
  transpose_cast<<<dim3(16, 64, 4), tb, 0, stream>>>(w2, w2t, 2048, 512, 1048576, 1048576);
  transpose_cast<<<dim3(2, 16, 1), tb, 0, stream>>>(down_w, dwt, 512, 64, 0, 0);
  transpose_cast<<<dim3(16, 2, 1), tb, 0, stream>>>(up_w, uwt, 64, 512, 0, 0);

  // ---- prologue (all-bf16 MFMA path) ----
  embed_kernel<<<4096, 512, 0, stream>>>(x_enc, x_mark, conv_w, conv_b,
                                         temp_w, temp_b, e_bf);
  gemm_bf16_t32<<<128, 256, 0, stream>>>(e_bf, dwt, down_b, tmp0_bf, 64, 512);
  pyr_conv<<<4 * 256, 64, 0, stream>>>(tmp0_bf, 0, 1024, pyrf_bf, 0, 336, 256,
                                       pyr_w, pyr_b, bn_g, bn_b);
  pyr_conv<<<4 * 64, 64, 0, stream>>>(pyrf_bf, 0, 336, pyrf_bf, 256, 336, 64,
                                      pyr_w + 16384, pyr_b + 64, bn_g + 64, bn_b + 64);
  pyr_conv<<<4 * 16, 64, 0, stream>>>(pyrf_bf, 256, 336, pyrf_bf, 320, 336, 16,
                                      pyr_w + 32768, pyr_b + 128, bn_g + 128, bn_b + 128);
  gemm_bf16_t32<<<8 * 42, 256, 0, stream>>>(pyrf_bf, uwt, up_b, pyru_bf, 512, 64);
  ln_concat<<<1360, 256, 0, stream>>>(e_bf, pyru_bf, norm_g, norm_b, seq_bf);

  // ---- layers ----
  for (int l = 0; l < 4; l++) {
    gemm_bf16_t64w8<<<24 * 86, 512, 0, stream>>>(seq_bf, qkvw + (size_t)l * 786432,
                                                 nullptr, qkv_bf, 1536, 512, 0);
    attn_sparse<<<5440, 512, 0, stream>>>(qkv_bf, o_bf);
    gemm_bf16_t32<<<8 * 172, 256, 0, stream>>>(o_bf, fcw + (size_t)l * 262144,
                                               fc_b + l * 512, t1, 512, 512);
    ln_add<<<1360, 256, 0, stream>>>(seq_bf, t1, ln1_g + l * 512, ln1_b + l * 512);
    gemm_bf16_t64w8<<<32 * 86, 512, 0, stream>>>(seq_bf, w1t + (size_t)l * 1048576,
                                                 b1 + l * 2048, th_bf, 2048, 512, 1);
    gemm_bf16_t32<<<8 * 172, 256, 0, stream>>>(th_bf, w2t + (size_t)l * 1048576,
                                               b2 + l * 512, t1, 512, 2048);
    ln_add<<<1360, 256, 0, stream>>>(seq_bf, t1, ln2_g + l * 512, ln2_b + l * 512);
  }
  gather_out<<<4096, 512, 0, stream>>>(seq_bf, (float*)d_out);
}